// Round 1
// baseline (1075.763 us; speedup 1.0000x reference)
//
#include <hip/hip_runtime.h>
#include <math.h>

// ---------------------------------------------------------------------------
// NeRF fused forward, fp32 baseline.
//   trilinear(grid) -> [32] -> relu dense 128 -> dense 16 (dfeat)
//   density = relu(dfeat[0])
//   fdir = [dfeat(16), d(3), sin(ang)(12), cos(ang)(12)] = 43
//   h2 = relu(fdir @ wc1) -> rgb = sigmoid(h2 @ wc2)
//   out[n] = {rgb, density}  (float4)
// Weights are read via wave-uniform indices -> scalar loads (s_load_dwordxN).
// wd1 and wc1 are pre-transposed into d_ws so per-neuron weights are
// contiguous (enables wide scalar loads).
// ---------------------------------------------------------------------------

__global__ void transpose_weights(const float* __restrict__ wd1,   // [32][128]
                                  const float* __restrict__ wc1,   // [43][128]
                                  float* __restrict__ wd1T,        // [128][32]
                                  float* __restrict__ wc1T)        // [128][43]
{
    int t = blockIdx.x * blockDim.x + threadIdx.x;
    int stride = gridDim.x * blockDim.x;
    for (int i = t; i < 32 * 128; i += stride) {
        int k = i >> 7;        // row in wd1
        int j = i & 127;       // col
        wd1T[j * 32 + k] = wd1[i];
    }
    for (int i = t; i < 43 * 128; i += stride) {
        int m = i / 128;
        int j = i % 128;
        wc1T[j * 43 + m] = wc1[i];
    }
}

__device__ __forceinline__ float sigmoidf_(float x) {
    return 1.0f / (1.0f + expf(-x));
}

__global__ __launch_bounds__(256) void nerf_fused(
    const float* __restrict__ coords,
    const float* __restrict__ ray_d,
    const float* __restrict__ grid,     // [128][128][128][32]
    const float* __restrict__ wd1T,     // [128][32]   (transposed)
    const float* __restrict__ bd1,      // [128]
    const float* __restrict__ wd2,      // [128][16]
    const float* __restrict__ bd2,      // [16]
    const float* __restrict__ wc1T,     // [128][43]   (transposed)
    const float* __restrict__ bc1,      // [128]
    const float* __restrict__ wc2,      // [128][3]
    const float* __restrict__ bc2,      // [3]
    float* __restrict__ out,            // [N][4]
    int N)
{
    int n = blockIdx.x * blockDim.x + threadIdx.x;
    if (n >= N) return;

    // ---------------- trilinear interpolation ----------------
    float cx = coords[3 * n + 0] * 127.0f;
    float cy = coords[3 * n + 1] * 127.0f;
    float cz = coords[3 * n + 2] * 127.0f;
    int ix = (int)floorf(cx); ix = ix < 0 ? 0 : (ix > 126 ? 126 : ix);
    int iy = (int)floorf(cy); iy = iy < 0 ? 0 : (iy > 126 ? 126 : iy);
    int iz = (int)floorf(cz); iz = iz < 0 ? 0 : (iz > 126 ? 126 : iz);
    float tx = cx - (float)ix;
    float ty = cy - (float)iy;
    float tz = cz - (float)iz;

    float feats[32];
#pragma unroll
    for (int q = 0; q < 32; ++q) feats[q] = 0.0f;

#pragma unroll
    for (int dx = 0; dx < 2; ++dx) {
        float wx = dx ? tx : 1.0f - tx;
#pragma unroll
        for (int dy = 0; dy < 2; ++dy) {
            float wy = dy ? ty : 1.0f - ty;
#pragma unroll
            for (int dz = 0; dz < 2; ++dz) {
                float wz = dz ? tz : 1.0f - tz;
                float w = wx * wy * wz;
                const float4* g = (const float4*)(grid +
                    ((((size_t)(ix + dx) * 128) + (iy + dy)) * 128 + (iz + dz)) * 32);
#pragma unroll
                for (int q = 0; q < 8; ++q) {
                    float4 v = g[q];
                    feats[4 * q + 0] = fmaf(w, v.x, feats[4 * q + 0]);
                    feats[4 * q + 1] = fmaf(w, v.y, feats[4 * q + 1]);
                    feats[4 * q + 2] = fmaf(w, v.z, feats[4 * q + 2]);
                    feats[4 * q + 3] = fmaf(w, v.w, feats[4 * q + 3]);
                }
            }
        }
    }

    // ---------------- layer 1 (32->128 relu) + layer 2 (128->16) fused ----
    // fdir[0..15] accumulates dfeat; [16..42] is the view embedding.
    float fdir[43];
#pragma unroll
    for (int d = 0; d < 16; ++d) fdir[d] = bd2[d];

#pragma unroll 2
    for (int j = 0; j < 128; ++j) {
        float hj = bd1[j];
        const float* wrow = wd1T + j * 32;
#pragma unroll
        for (int k = 0; k < 32; ++k) hj = fmaf(feats[k], wrow[k], hj);
        hj = fmaxf(hj, 0.0f);
        const float* w2row = wd2 + j * 16;
#pragma unroll
        for (int d = 0; d < 16; ++d) fdir[d] = fmaf(hj, w2row[d], fdir[d]);
    }

    float density = fmaxf(fdir[0], 0.0f);

    // ---------------- direction embedding ----------------
    float dxv = ray_d[3 * n + 0];
    float dyv = ray_d[3 * n + 1];
    float dzv = ray_d[3 * n + 2];
    fdir[16] = dxv; fdir[17] = dyv; fdir[18] = dzv;
#pragma unroll
    for (int f = 0; f < 4; ++f) {
        float fr = (float)(1 << f);
        float ax = dxv * fr, ay = dyv * fr, az = dzv * fr;
        fdir[19 + f * 3 + 0] = sinf(ax);
        fdir[19 + f * 3 + 1] = sinf(ay);
        fdir[19 + f * 3 + 2] = sinf(az);
        fdir[31 + f * 3 + 0] = cosf(ax);
        fdir[31 + f * 3 + 1] = cosf(ay);
        fdir[31 + f * 3 + 2] = cosf(az);
    }

    // ---------------- layer 3 (43->128 relu) + layer 4 (128->3) fused ------
    float rgb0 = bc2[0], rgb1 = bc2[1], rgb2 = bc2[2];
#pragma unroll 2
    for (int j = 0; j < 128; ++j) {
        float h2 = bc1[j];
        const float* wrow = wc1T + j * 43;
#pragma unroll
        for (int m = 0; m < 43; ++m) h2 = fmaf(fdir[m], wrow[m], h2);
        h2 = fmaxf(h2, 0.0f);
        rgb0 = fmaf(h2, wc2[j * 3 + 0], rgb0);
        rgb1 = fmaf(h2, wc2[j * 3 + 1], rgb1);
        rgb2 = fmaf(h2, wc2[j * 3 + 2], rgb2);
    }

    float4 o;
    o.x = sigmoidf_(rgb0);
    o.y = sigmoidf_(rgb1);
    o.z = sigmoidf_(rgb2);
    o.w = density;
    ((float4*)out)[n] = o;
}

extern "C" void kernel_launch(void* const* d_in, const int* in_sizes, int n_in,
                              void* d_out, int out_size, void* d_ws, size_t ws_size,
                              hipStream_t stream) {
    const float* coords = (const float*)d_in[0];
    const float* ray_d  = (const float*)d_in[1];
    const float* grid   = (const float*)d_in[2];
    const float* wd1    = (const float*)d_in[3];
    const float* bd1    = (const float*)d_in[4];
    const float* wd2    = (const float*)d_in[5];
    const float* bd2    = (const float*)d_in[6];
    const float* wc1    = (const float*)d_in[7];
    const float* bc1    = (const float*)d_in[8];
    const float* wc2    = (const float*)d_in[9];
    const float* bc2    = (const float*)d_in[10];
    float* out = (float*)d_out;

    int N = in_sizes[0] / 3;

    float* ws   = (float*)d_ws;
    float* wd1T = ws;            // 128*32  = 4096 floats
    float* wc1T = ws + 4096;     // 128*43  = 5504 floats

    transpose_weights<<<32, 256, 0, stream>>>(wd1, wc1, wd1T, wc1T);

    int blocks = (N + 255) / 256;
    nerf_fused<<<blocks, 256, 0, stream>>>(coords, ray_d, grid,
                                           wd1T, bd1, wd2, bd2,
                                           wc1T, bc1, wc2, bc2,
                                           out, N);
}

// Round 2
// 415.897 us; speedup vs baseline: 2.5866x; 2.5866x over previous
//
#include <hip/hip_runtime.h>
#include <hip/hip_bf16.h>
#include <math.h>

typedef __attribute__((ext_vector_type(8))) __bf16 bf16x8;
typedef __attribute__((ext_vector_type(4))) __bf16 bf16x4;
typedef __attribute__((ext_vector_type(4))) float f32x4;

// LDS layout (per block, waves cooperate on one 64-point tile)
//  A tile: [64 rows][72 bf16]  stride 144 B   cols 0-31 = feats_hi, 32-63 = feats_lo
//  H tile: [64 rows][136 bf16] stride 272 B   h (L1 out) then reused for h2 (L3 out)
//  F tile: [64 rows][72 bf16]  stride 144 B   fdir: 0-15 dfeat, 16-18 d, 19-30 sin,
//                                             31-42 cos, 43-63 zero pad
#define LDS_A_OFF   0
#define LDS_H_OFF   9216
#define LDS_F_OFF   26624
#define LDS_TOTAL   35840

// ---------------------------------------------------------------------------
// Pack all MLP weights into MFMA B-fragment-ready bf16 layout in ws.
// Frag f occupies 1024 B: [lane 0..63][8 bf16]; lane l holds
// B[k = (l>>4)*8 + j][n = l&15] of the 32(K)x16(N) sub-tile.
//   frags 0-7  : L1 wd1[32][128], n-tile 0..7, 1 K-tile
//   frags 8-11 : L2 wd2[128][16], K-tile 0..3
//   frags 12-27: L3 wc1 padded [64][128] (rows 43-63 zero), (n*2 + kt)
//   frags 28-31: L4 wc2 padded [128][16] (cols 3-15 zero), K-tile 0..3
// ---------------------------------------------------------------------------
__global__ void pack_weights(const float* __restrict__ wd1,
                             const float* __restrict__ wd2,
                             const float* __restrict__ wc1,
                             const float* __restrict__ wc2,
                             __bf16* __restrict__ wp)
{
    int t0 = threadIdx.x;
    for (int it = 0; it < 8; ++it) {
        int t = it * 256 + t0;           // 0..2047 = 32 frags * 64 lanes
        int frag = t >> 6;
        int lane = t & 63;
        int kg = lane >> 4;
        int c  = lane & 15;
        for (int j = 0; j < 8; ++j) {
            int k = kg * 8 + j;          // 0..31 within K-tile
            float v;
            if (frag < 8) {
                v = wd1[k * 128 + frag * 16 + c];
            } else if (frag < 12) {
                v = wd2[((frag - 8) * 32 + k) * 16 + c];
            } else if (frag < 28) {
                int f = frag - 12;
                int kk = (f & 1) * 32 + k;          // 0..63
                v = (kk < 43) ? wc1[kk * 128 + (f >> 1) * 16 + c] : 0.0f;
            } else {
                int kk = (frag - 28) * 32 + k;      // 0..127
                v = (c < 3) ? wc2[kk * 3 + c] : 0.0f;
            }
            wp[frag * 512 + lane * 8 + j] = (__bf16)v;
        }
    }
}

// ---------------------------------------------------------------------------
// Fused NeRF forward: gather + 4 MFMA layers.
// ---------------------------------------------------------------------------
__global__ __launch_bounds__(256) void nerf_mfma(
    const float* __restrict__ coords,
    const float* __restrict__ ray_d,
    const float* __restrict__ grid,     // [128][128][128][32] f32
    const float* __restrict__ bd1,
    const float* __restrict__ bd2,
    const float* __restrict__ bc1,
    const float* __restrict__ bc2,
    const __bf16* __restrict__ wp,      // packed frags (32 KB)
    float* __restrict__ out,            // [N][4]
    int ntiles)
{
    __shared__ __align__(16) char lds[LDS_TOTAL];
    const int tid  = threadIdx.x;
    const int lane = tid & 63;
    const int wid  = tid >> 6;
    const int c    = lane & 15;        // MFMA col / row-in-16 index
    const int kg   = lane >> 4;        // MFMA k-group / row-group

    // ---- hoist weight fragments & biases into registers -------------------
    const bf16x8* wpv = (const bf16x8*)wp;           // [frag*64 + lane]
    const int n0 = wid * 2, n1 = wid * 2 + 1;        // this wave's N-tiles
    bf16x8 B1a = wpv[n0 * 64 + lane];
    bf16x8 B1b = wpv[n1 * 64 + lane];
    bf16x8 B2[4], B4[4], B3a[2], B3b[2];
#pragma unroll
    for (int kt = 0; kt < 4; ++kt) B2[kt] = wpv[(8 + kt) * 64 + lane];
#pragma unroll
    for (int kt = 0; kt < 2; ++kt) {
        B3a[kt] = wpv[(12 + n0 * 2 + kt) * 64 + lane];
        B3b[kt] = wpv[(12 + n1 * 2 + kt) * 64 + lane];
    }
#pragma unroll
    for (int kt = 0; kt < 4; ++kt) B4[kt] = wpv[(28 + kt) * 64 + lane];

    const float bias1a = bd1[n0 * 16 + c];
    const float bias1b = bd1[n1 * 16 + c];
    const float bias2  = bd2[c];
    const float bias3a = bc1[n0 * 16 + c];
    const float bias3b = bc1[n1 * 16 + c];
    const float bias4  = (c < 3) ? bc2[c] : 0.0f;

    // ---- zero F pad cols 43..63 (written once, never overwritten) ---------
    for (int i = tid; i < 64 * 21; i += 256) {
        int row = i / 21, col = 43 + i % 21;
        *(__bf16*)(lds + LDS_F_OFF + row * 144 + col * 2) = (__bf16)0.0f;
    }

    const int wpt = wid * 16;          // wave's local point base

    for (int tile = blockIdx.x; tile < ntiles; tile += gridDim.x) {
        const int pbase = tile * 64;

        // ================= phase 0: trilinear gather =======================
        // 8 lanes per point: lane = q*8 + sub; 2 rounds of 8 points.
        {
            float cval = (lane < 48) ? coords[(size_t)(pbase + wpt) * 3 + lane] : 0.0f;
            const int sub = lane & 7;
#pragma unroll
            for (int r = 0; r < 2; ++r) {
                int q = r * 8 + (lane >> 3);            // local point 0..15
                float cx = __shfl(cval, 3 * q + 0) * 127.0f;
                float cy = __shfl(cval, 3 * q + 1) * 127.0f;
                float cz = __shfl(cval, 3 * q + 2) * 127.0f;
                int ix = (int)floorf(cx); ix = ix < 0 ? 0 : (ix > 126 ? 126 : ix);
                int iy = (int)floorf(cy); iy = iy < 0 ? 0 : (iy > 126 ? 126 : iy);
                int iz = (int)floorf(cz); iz = iz < 0 ? 0 : (iz > 126 ? 126 : iz);
                float tx = cx - (float)ix;
                float ty = cy - (float)iy;
                float tz = cz - (float)iz;

                f32x4 facc = {0.0f, 0.0f, 0.0f, 0.0f};
#pragma unroll
                for (int cc = 0; cc < 8; ++cc) {
                    int ddx = (cc >> 2) & 1, ddy = (cc >> 1) & 1, ddz = cc & 1;
                    float w = (ddx ? tx : 1.0f - tx) *
                              (ddy ? ty : 1.0f - ty) *
                              (ddz ? tz : 1.0f - tz);
                    int idx = ((ix + ddx) << 14) + ((iy + ddy) << 7) + (iz + ddz);
                    f32x4 v = *((const f32x4*)(grid + (size_t)idx * 32) + sub);
                    facc = facc + v * w;
                }
                // split fp32 feats -> hi + lo bf16 (extended precision for L1)
                bf16x4 hi, lo;
#pragma unroll
                for (int e = 0; e < 4; ++e) {
                    __bf16 h = (__bf16)facc[e];
                    hi[e] = h;
                    lo[e] = (__bf16)(facc[e] - (float)h);
                }
                char* arow = lds + LDS_A_OFF + (wpt + q) * 144;
                *(bf16x4*)(arow + sub * 8)      = hi;
                *(bf16x4*)(arow + 64 + sub * 8) = lo;
            }
        }
        __syncthreads();   // B0: A tile ready

        // ================= phase 1: L1 (32 -> 128, relu) ===================
        {
            f32x4 h[4][2];
#pragma unroll
            for (int m = 0; m < 4; ++m) {
                h[m][0] = (f32x4){bias1a, bias1a, bias1a, bias1a};
                h[m][1] = (f32x4){bias1b, bias1b, bias1b, bias1b};
            }
#pragma unroll
            for (int m = 0; m < 4; ++m) {
                const char* ab = lds + LDS_A_OFF + (m * 16 + c) * 144 + kg * 16;
                bf16x8 Ahi = *(const bf16x8*)(ab);
                bf16x8 Alo = *(const bf16x8*)(ab + 64);
                h[m][0] = __builtin_amdgcn_mfma_f32_16x16x32_bf16(Alo, B1a, h[m][0], 0, 0, 0);
                h[m][0] = __builtin_amdgcn_mfma_f32_16x16x32_bf16(Ahi, B1a, h[m][0], 0, 0, 0);
                h[m][1] = __builtin_amdgcn_mfma_f32_16x16x32_bf16(Alo, B1b, h[m][1], 0, 0, 0);
                h[m][1] = __builtin_amdgcn_mfma_f32_16x16x32_bf16(Ahi, B1b, h[m][1], 0, 0, 0);
            }
            // relu -> bf16 -> H tile
#pragma unroll
            for (int m = 0; m < 4; ++m) {
#pragma unroll
                for (int nn = 0; nn < 2; ++nn) {
                    int col = (nn ? n1 : n0) * 16 + c;
#pragma unroll
                    for (int i = 0; i < 4; ++i) {
                        int row = m * 16 + kg * 4 + i;
                        float v = fmaxf(h[m][nn][i], 0.0f);
                        *(__bf16*)(lds + LDS_H_OFF + row * 272 + col * 2) = (__bf16)v;
                    }
                }
            }
        }
        __syncthreads();   // B1: H ready

        // ================= phase 2: L2 (128 -> 16), density, dfeat->F ======
        {
            f32x4 d2 = {bias2, bias2, bias2, bias2};
#pragma unroll
            for (int kt = 0; kt < 4; ++kt) {
                bf16x8 A = *(const bf16x8*)(lds + LDS_H_OFF + (wpt + c) * 272 + kt * 64 + kg * 16);
                d2 = __builtin_amdgcn_mfma_f32_16x16x32_bf16(A, B2[kt], d2, 0, 0, 0);
            }
#pragma unroll
            for (int i = 0; i < 4; ++i) {
                int row = wpt + kg * 4 + i;     // local point
                *(__bf16*)(lds + LDS_F_OFF + row * 144 + c * 2) = (__bf16)d2[i];
                if (c == 0)                      // density from fp32 accumulator
                    out[(size_t)(pbase + row) * 4 + 3] = fmaxf(d2[i], 0.0f);
            }
        }

        // ================= phase 3: view embedding -> F ====================
        {
            float rv = (lane < 48) ? ray_d[(size_t)(pbase + wpt) * 3 + lane] : 0.0f;
            float ddx = __shfl(rv, 3 * c + 0);
            float ddy = __shfl(rv, 3 * c + 1);
            float ddz = __shfl(rv, 3 * c + 2);
            char* Frow = lds + LDS_F_OFF + (wpt + c) * 144;
            if (kg == 0) {
                *(__bf16*)(Frow + 16 * 2) = (__bf16)ddx;
                *(__bf16*)(Frow + 17 * 2) = (__bf16)ddy;
                *(__bf16*)(Frow + 18 * 2) = (__bf16)ddz;
            }
            float fr = (float)(1 << kg);
            float ax = ddx * fr, ay = ddy * fr, az = ddz * fr;
            *(__bf16*)(Frow + (19 + 3 * kg) * 2)     = (__bf16)sinf(ax);
            *(__bf16*)(Frow + (19 + 3 * kg) * 2 + 2) = (__bf16)sinf(ay);
            *(__bf16*)(Frow + (19 + 3 * kg) * 2 + 4) = (__bf16)sinf(az);
            *(__bf16*)(Frow + (31 + 3 * kg) * 2)     = (__bf16)cosf(ax);
            *(__bf16*)(Frow + (31 + 3 * kg) * 2 + 2) = (__bf16)cosf(ay);
            *(__bf16*)(Frow + (31 + 3 * kg) * 2 + 4) = (__bf16)cosf(az);
        }
        __syncthreads();   // B2: F ready; H reads done

        // ================= phase 4: L3 (64 -> 128, relu) ===================
        {
            f32x4 h2[4][2];
#pragma unroll
            for (int m = 0; m < 4; ++m) {
                h2[m][0] = (f32x4){bias3a, bias3a, bias3a, bias3a};
                h2[m][1] = (f32x4){bias3b, bias3b, bias3b, bias3b};
            }
#pragma unroll
            for (int m = 0; m < 4; ++m) {
#pragma unroll
                for (int kt = 0; kt < 2; ++kt) {
                    bf16x8 A = *(const bf16x8*)(lds + LDS_F_OFF + (m * 16 + c) * 144 + kt * 64 + kg * 16);
                    h2[m][0] = __builtin_amdgcn_mfma_f32_16x16x32_bf16(A, B3a[kt], h2[m][0], 0, 0, 0);
                    h2[m][1] = __builtin_amdgcn_mfma_f32_16x16x32_bf16(A, B3b[kt], h2[m][1], 0, 0, 0);
                }
            }
            // relu -> bf16 -> H tile (reused as h2)
#pragma unroll
            for (int m = 0; m < 4; ++m) {
#pragma unroll
                for (int nn = 0; nn < 2; ++nn) {
                    int col = (nn ? n1 : n0) * 16 + c;
#pragma unroll
                    for (int i = 0; i < 4; ++i) {
                        int row = m * 16 + kg * 4 + i;
                        float v = fmaxf(h2[m][nn][i], 0.0f);
                        *(__bf16*)(lds + LDS_H_OFF + row * 272 + col * 2) = (__bf16)v;
                    }
                }
            }
        }
        __syncthreads();   // B3: h2 ready

        // ================= phase 5: L4 (128 -> 3), sigmoid, store ==========
        {
            f32x4 o4 = {bias4, bias4, bias4, bias4};
#pragma unroll
            for (int kt = 0; kt < 4; ++kt) {
                bf16x8 A = *(const bf16x8*)(lds + LDS_H_OFF + (wpt + c) * 272 + kt * 64 + kg * 16);
                o4 = __builtin_amdgcn_mfma_f32_16x16x32_bf16(A, B4[kt], o4, 0, 0, 0);
            }
            if (c < 3) {
#pragma unroll
                for (int i = 0; i < 4; ++i) {
                    int row = wpt + kg * 4 + i;
                    float s = 1.0f / (1.0f + expf(-o4[i]));
                    out[(size_t)(pbase + row) * 4 + c] = s;
                }
            }
        }
        __syncthreads();   // B4 separates this tile's LDS reads from next gather/L1
    }
}

extern "C" void kernel_launch(void* const* d_in, const int* in_sizes, int n_in,
                              void* d_out, int out_size, void* d_ws, size_t ws_size,
                              hipStream_t stream) {
    const float* coords = (const float*)d_in[0];
    const float* ray_d  = (const float*)d_in[1];
    const float* grid   = (const float*)d_in[2];
    const float* wd1    = (const float*)d_in[3];
    const float* bd1    = (const float*)d_in[4];
    const float* wd2    = (const float*)d_in[5];
    const float* bd2    = (const float*)d_in[6];
    const float* wc1    = (const float*)d_in[7];
    const float* bc1    = (const float*)d_in[8];
    const float* wc2    = (const float*)d_in[9];
    const float* bc2    = (const float*)d_in[10];
    float* out = (float*)d_out;

    int N = in_sizes[0] / 3;
    int ntiles = N >> 6;

    __bf16* wp = (__bf16*)d_ws;   // 32 KB packed weights

    pack_weights<<<1, 256, 0, stream>>>(wd1, wd2, wc1, wc2, wp);

    int blocks = ntiles < 8192 ? ntiles : 8192;
    nerf_mfma<<<blocks, 256, 0, stream>>>(coords, ray_d, grid,
                                          bd1, bd2, bc1, bc2,
                                          wp, out, ntiles);
}